// Round 5
// baseline (1818.758 us; speedup 1.0000x reference)
//
#include <hip/hip_runtime.h>
#include <math.h>

// Problem constants: V=32000 D=512 H=512 L=2 B=64 S=64 -> T=Te=63
#define NEGV -1000000000.0f

typedef unsigned short u16;
typedef __attribute__((ext_vector_type(8))) short bf16x8;
typedef __attribute__((ext_vector_type(4))) float f32x4;

__device__ __forceinline__ u16 f2bf(float f){
  union { float f; unsigned u; } v; v.f = f;
  unsigned u = v.u;
  unsigned r = (u + 0x7fffu + ((u >> 16) & 1u)) >> 16;
  return (u16)r;
}
__device__ __forceinline__ float bf2f(u16 b){
  union { unsigned u; float f; } v; v.u = ((unsigned)b) << 16;
  return v.f;
}
__device__ __forceinline__ float sigmf(float x){ return 1.f / (1.f + __expf(-x)); }
__device__ __forceinline__ float tanhf_(float x){
  float e = __expf(-2.f * fabsf(x));
  float t = (1.f - e) / (1.f + e);
  return x >= 0.f ? t : -t;
}
__device__ __forceinline__ float wred64(float v){
  #pragma unroll
  for (int m = 32; m; m >>= 1) v += __shfl_xor(v, m, 64);
  return v;
}
__device__ __forceinline__ float wmax64(float v){
  #pragma unroll
  for (int m = 32; m; m >>= 1) v = fmaxf(v, __shfl_xor(v, m, 64));
  return v;
}

// ---- async global->LDS (16B/lane). LDS dest is wave-uniform base + lane*16. ----
typedef const __attribute__((address_space(1))) unsigned int* gas_ptr;
typedef __attribute__((address_space(3))) unsigned int* las_ptr;
__device__ __forceinline__ void gl_lds16(const u16* g, u16* l){
  __builtin_amdgcn_global_load_lds((gas_ptr)g, (las_ptr)l, 16, 0, 0);
}

// ---- agent-scope (sc1) write-through 2B store: h-ring data bypasses L1/L2 ----
__device__ __forceinline__ void st_sc1_u16(u16* p, unsigned v){
  asm volatile("global_store_short %0, %1, off sc1" :: "v"(p), "v"(v) : "memory");
}

// ---------------- prep: fp32 -> bf16 weight copies + bias sums ----------------
__global__ __launch_bounds__(256) void k_prep(
    const float* wih, const float* whh, const float* we, const float* wh,
    const float* fcw, const float* enc, const float* bih, const float* bhh,
    u16* wihb, u16* whhb, u16* web, u16* whb, u16* fcwb, u16* encb, float* b01)
{
  const long n0 = 2097152, n1 = 2097152, n2 = 262144, n3 = 262144;
  const long n4 = 32768000, n5 = 2064384, n6 = 4096;
  const long total = n0 + n1 + n2 + n3 + n4 + n5 + n6;
  long stride = (long)gridDim.x * 256;
  for (long i = (long)blockIdx.x * 256 + threadIdx.x; i < total; i += stride){
    long j = i;
    if (j < n0){ wihb[j] = f2bf(wih[j]); continue; } j -= n0;
    if (j < n1){ whhb[j] = f2bf(whh[j]); continue; } j -= n1;
    if (j < n2){ web[j]  = f2bf(we[j]);  continue; } j -= n2;
    if (j < n3){ whb[j]  = f2bf(wh[j]);  continue; } j -= n3;
    if (j < n4){ fcwb[j] = f2bf(fcw[j]); continue; } j -= n4;
    if (j < n5){ encb[j] = f2bf(enc[j]); continue; } j -= n5;
    b01[j] = bih[j] + bhh[j];   // j<2048: layer0 bias sum; 2048..4095: layer1
  }
}

// ---------------- embedding gather -> bf16 ----------------
__global__ __launch_bounds__(256) void k_embed(const int* X, const float* emb, u16* ebf){
  int row = blockIdx.x;            // t*64 + b
  int t = row >> 6, b = row & 63;
  int tok = X[b * 64 + t];         // X is (B=64, S=64)
  const float* src = emb + (long)tok * 512;
  u16* dst = ebf + (long)row * 512;
  for (int j = threadIdx.x; j < 512; j += 256) dst[j] = f2bf(src[j]);
}

// ---------------- generic bf16 GEMM: C(M,N) = A(M,K) @ B(N,K)^T + bias (fp32 out) ----------------
__global__ __launch_bounds__(256) void gemm_bt(
    const u16* Am, int lda, const u16* Bm, int ldb,
    float* C, int ldc, const float* bias, int K)
{
  __shared__ u16 sA[64 * 32], sB[64 * 32];
  int tm = blockIdx.x, tn = blockIdx.y;
  int tid = threadIdx.x;
  int wave = tid >> 6, lane = tid & 63;
  int wm = wave >> 1, wn = wave & 1;
  int q = lane >> 4, cl = lane & 15;
  f32x4 acc[2][2];
  #pragma unroll
  for (int i = 0; i < 2; i++)
    #pragma unroll
    for (int j = 0; j < 2; j++) acc[i][j] = (f32x4){0.f, 0.f, 0.f, 0.f};

  int r = tid >> 2, ck = tid & 3;
  const u16* Ags = Am + (long)(tm * 64 + r) * lda + ck * 8;
  const u16* Bgs = Bm + (long)(tn * 64 + r) * ldb + ck * 8;
  // LDS layout is linear in tid (byte off = tid*16) -> direct global_load_lds
  u16* sAw = &sA[wave * 512];
  u16* sBw = &sB[wave * 512];

  for (int kt = 0; kt < K; kt += 32){
    gl_lds16(Ags + kt, sAw);
    gl_lds16(Bgs + kt, sBw);
    __syncthreads();
    #pragma unroll
    for (int i = 0; i < 2; i++){
      bf16x8 af = *(const bf16x8*)&sA[(wm * 32 + i * 16 + cl) * 32 + q * 8];
      #pragma unroll
      for (int j = 0; j < 2; j++){
        bf16x8 bfv = *(const bf16x8*)&sB[(wn * 32 + j * 16 + cl) * 32 + q * 8];
        acc[i][j] = __builtin_amdgcn_mfma_f32_16x16x32_bf16(af, bfv, acc[i][j], 0, 0, 0);
      }
    }
    __syncthreads();
  }
  #pragma unroll
  for (int i = 0; i < 2; i++)
    #pragma unroll
    for (int j = 0; j < 2; j++){
      int colg = tn * 64 + wn * 32 + j * 16 + cl;
      float bv = bias ? bias[colg] : 0.f;
      #pragma unroll
      for (int rr = 0; rr < 4; rr++){
        int rowg = tm * 64 + wm * 32 + i * 16 + q * 4 + rr;
        C[(long)rowg * ldc + colg] = acc[i][j][rr] + bv;
      }
    }
}

// ---------------- same GEMM but bf16 output (for x0 gate pre-activations) ----------------
__global__ __launch_bounds__(256) void gemm_btb(
    const u16* Am, int lda, const u16* Bm, int ldb,
    u16* C, int ldc, const float* bias, int K)
{
  __shared__ u16 sA[64 * 32], sB[64 * 32];
  int tm = blockIdx.x, tn = blockIdx.y;
  int tid = threadIdx.x;
  int wave = tid >> 6, lane = tid & 63;
  int wm = wave >> 1, wn = wave & 1;
  int q = lane >> 4, cl = lane & 15;
  f32x4 acc[2][2];
  #pragma unroll
  for (int i = 0; i < 2; i++)
    #pragma unroll
    for (int j = 0; j < 2; j++) acc[i][j] = (f32x4){0.f, 0.f, 0.f, 0.f};

  int r = tid >> 2, ck = tid & 3;
  const u16* Ags = Am + (long)(tm * 64 + r) * lda + ck * 8;
  const u16* Bgs = Bm + (long)(tn * 64 + r) * ldb + ck * 8;
  u16* sAw = &sA[wave * 512];
  u16* sBw = &sB[wave * 512];

  for (int kt = 0; kt < K; kt += 32){
    gl_lds16(Ags + kt, sAw);
    gl_lds16(Bgs + kt, sBw);
    __syncthreads();
    #pragma unroll
    for (int i = 0; i < 2; i++){
      bf16x8 af = *(const bf16x8*)&sA[(wm * 32 + i * 16 + cl) * 32 + q * 8];
      #pragma unroll
      for (int j = 0; j < 2; j++){
        bf16x8 bfv = *(const bf16x8*)&sB[(wn * 32 + j * 16 + cl) * 32 + q * 8];
        acc[i][j] = __builtin_amdgcn_mfma_f32_16x16x32_bf16(af, bfv, acc[i][j], 0, 0, 0);
      }
    }
    __syncthreads();
  }
  #pragma unroll
  for (int i = 0; i < 2; i++)
    #pragma unroll
    for (int j = 0; j < 2; j++){
      int colg = tn * 64 + wn * 32 + j * 16 + cl;
      float bv = bias ? bias[colg] : 0.f;
      #pragma unroll
      for (int rr = 0; rr < 4; rr++){
        int rowg = tm * 64 + wm * 32 + i * 16 + q * 4 + rr;
        C[(long)rowg * ldc + colg] = f2bf(acc[i][j][rr] + bv);
      }
    }
}

// ---------------- merged 2-layer pipelined LSTM: 32 WGs, ONE rendezvous per tick ----------------
// WG i owns h-cols [16i, 16i+16) of BOTH layers. Tick t: compute h0(t) and h1(t-1).
// Rendezvous: done[t] counter at MALL; each WG atomicAdds after its stores; waiters
// poll the SINGLE word done[t-1] (all lanes same addr -> 1 MALL request/iter/WG).
// h rings depth 8 (lockstep makes spread <1 tick; slots t-1,t-2 read, t,t-1 written).
// Coherence: sc1 write-through stores + sc1 direct loads; no wbl2/inv anywhere.
// LDS: Whh0 + Whh1 slices (128 KB). Wih1 slice streamed from L2 every tick.

// issue 16 sc1 b128 loads (one K-pass of A-fragments), no wait
#define ISSUE_RING_FRAGS(afr, Ab)                                              \
  {                                                                            \
    _Pragma("unroll")                                                          \
    for (int kt = 0; kt < 16; kt++)                                            \
      asm volatile("global_load_dwordx4 %0, %1, off offset:%2 sc1"             \
                   : "=v"(afr[kt]) : "v"(Ab), "i"(kt * 64));                   \
  }
#define WAITCNT_VM(N)                                                          \
  { asm volatile("s_waitcnt vmcnt(" #N ")" ::: "memory");                      \
    __builtin_amdgcn_sched_barrier(0); }

__global__ __launch_bounds__(256, 1) void lstm_pipe(
    const u16* whh0, const u16* wih1, const u16* whh1,
    const u16* x0b, const float* b1s,
    u16* ring0, u16* ring1, u16* feat, int* done)
{
  __shared__ u16 sW0[32768];   // Whh0 slice (L0 recurrent B)
  __shared__ u16 sW1[32768];   // Whh1 slice (L1 recurrent B)
  int wg = blockIdx.x;         // 0..31
  int cc = wg * 16;
  int tid = threadIdx.x;
  int wave = tid >> 6, lane = tid & 63;
  int q = lane >> 4, cl = lane & 15;
  int j = cc + cl;

  // one-time weight stage (fragment-contiguous: unit (kt*4+q)*4+g holds 16 rows x 8 elems)
  for (int ch = tid; ch < 4096; ch += 256){
    int row = ch >> 6, c = ch & 63;
    int g = row >> 4, r = row & 15;
    *(uint4*)&sW0[((c * 4 + g) * 16 + r) * 8] =
        *(const uint4*)&whh0[(long)(g * 512 + cc + r) * 512 + c * 8];
    *(uint4*)&sW1[((c * 4 + g) * 16 + r) * 8] =
        *(const uint4*)&whh1[(long)(g * 512 + cc + r) * 512 + c * 8];
  }
  __syncthreads();

  float cst0[4] = {0.f, 0.f, 0.f, 0.f};   // layer0 c-state slice
  float cst1[4] = {0.f, 0.f, 0.f, 0.f};   // layer1 c-state slice
  float bg[4];
  #pragma unroll
  for (int g = 0; g < 4; g++) bg[g] = b1s[g * 512 + j];

  int foff = (wave * 16 + cl) * 512 + q * 8;           // A-fragment offset in a ring slot
  const u16* wbase = wih1 + (long)(cc + cl) * 512 + q * 8;   // Wih1 B-frag row base

  for (int t = 0; t < 64; t++){
    // prefetch x0 gate slice for L0 (static data, cached) BEFORE the wait
    float xg[4][4];
    if (t < 63){
      #pragma unroll
      for (int rr = 0; rr < 4; rr++){
        int s = wave * 16 + q * 4 + rr;
        const u16* xr = x0b + (long)(t * 64 + s) * 2048 + j;
        #pragma unroll
        for (int g = 0; g < 4; g++) xg[g][rr] = bf2f(xr[g * 512]);
      }
    }
    // ---- single rendezvous: all 32 WGs posted tick t-1 ----
    if (t > 0){
      if (tid < 64){
        const int* dp = done + (t - 1);
        for (;;){
          int v = __hip_atomic_load(dp, __ATOMIC_RELAXED, __HIP_MEMORY_SCOPE_AGENT);
          if (__ballot(v >= 32)) break;
          __builtin_amdgcn_s_sleep(1);   // bound spin-issue rate at the MALL
        }
      }
      __syncthreads();
    }

    // issue both ring reads (h0(t-1) and h1(t-2)); zeros pre-seeded for t<=0 cases
    bf16x8 a0[16], a1[16];
    const u16* Ab0 = ring0 + ((t + 7) & 7) * 32768 + foff;   // h0(t-1)
    const u16* Ab1 = ring1 + ((t + 6) & 7) * 32768 + foff;   // h1(t-2)
    ISSUE_RING_FRAGS(a0, Ab0);
    ISSUE_RING_FRAGS(a1, Ab1);
    WAITCNT_VM(16);                      // a0 landed; a1 still in flight

    // ---- L0 pass: h0(t) = LSTM0(x0(t), h0(t-1)) ----
    if (t < 63){
      f32x4 acc0[4];
      #pragma unroll
      for (int g = 0; g < 4; g++) acc0[g] = (f32x4){0.f, 0.f, 0.f, 0.f};
      #pragma unroll
      for (int kt = 0; kt < 16; kt++)
        #pragma unroll
        for (int g = 0; g < 4; g++){
          bf16x8 bfv = *(const bf16x8*)&sW0[(((kt * 4 + q) * 4 + g) * 16 + cl) * 8];
          acc0[g] = __builtin_amdgcn_mfma_f32_16x16x32_bf16(a0[kt], bfv, acc0[g], 0, 0, 0);
        }
      u16* hn = ring0 + (t & 7) * 32768;
      #pragma unroll
      for (int rr = 0; rr < 4; rr++){
        int s = wave * 16 + q * 4 + rr;
        float gi = acc0[0][rr] + xg[0][rr];
        float gf = acc0[1][rr] + xg[1][rr];
        float gg = acc0[2][rr] + xg[2][rr];
        float go = acc0[3][rr] + xg[3][rr];
        float cn = sigmf(gf) * cst0[rr] + sigmf(gi) * tanhf_(gg);
        cst0[rr] = cn;
        st_sc1_u16(hn + s * 512 + j, (unsigned)f2bf(sigmf(go) * tanhf_(cn)));
      }
    }

    // ---- L1: h1(t-1) = LSTM1(h0(t-1), h1(t-2)); input pass reuses a0 ----
    if (t > 0){
      f32x4 acc1[4];
      #pragma unroll
      for (int g = 0; g < 4; g++) acc1[g] = (f32x4){0.f, 0.f, 0.f, 0.f};
      // input term: a0 x Wih1 (B streamed from L2, offsets fold into 4 base addrs)
      #pragma unroll
      for (int kt = 0; kt < 16; kt++)
        #pragma unroll
        for (int g = 0; g < 4; g++){
          bf16x8 bfv = *(const bf16x8*)(wbase + (long)g * 262144 + kt * 32);
          acc1[g] = __builtin_amdgcn_mfma_f32_16x16x32_bf16(a0[kt], bfv, acc1[g], 0, 0, 0);
        }
      WAITCNT_VM(0);                     // a1 landed (hidden under the two passes above)
      #pragma unroll
      for (int kt = 0; kt < 16; kt++)
        #pragma unroll
        for (int g = 0; g < 4; g++){
          bf16x8 bfv = *(const bf16x8*)&sW1[(((kt * 4 + q) * 4 + g) * 16 + cl) * 8];
          acc1[g] = __builtin_amdgcn_mfma_f32_16x16x32_bf16(a1[kt], bfv, acc1[g], 0, 0, 0);
        }
      u16* hn = ring1 + ((t + 7) & 7) * 32768;
      #pragma unroll
      for (int rr = 0; rr < 4; rr++){
        int s = wave * 16 + q * 4 + rr;
        float gi = acc1[0][rr] + bg[0];
        float gf = acc1[1][rr] + bg[1];
        float gg = acc1[2][rr] + bg[2];
        float go = acc1[3][rr] + bg[3];
        float cn = sigmf(gf) * cst1[rr] + sigmf(gi) * tanhf_(gg);
        cst1[rr] = cn;
        u16 hb = f2bf(sigmf(go) * tanhf_(cn));
        st_sc1_u16(hn + s * 512 + j, (unsigned)hb);
        feat[(long)((t - 1) * 64 + s) * 1024 + j] = hb;   // top_{t-1}
      }
    }

    // drain ALL stores (incl. inline-asm sc1 stores), then post this tick
    asm volatile("s_waitcnt vmcnt(0)" ::: "memory");
    __syncthreads();
    if (tid == 0)
      (void)__hip_atomic_fetch_add(done + t, 1, __ATOMIC_RELAXED, __HIP_MEMORY_SCOPE_AGENT);
  }
}

// ---------------- attention scores: s[t,b,e] = sum_h vw[h]*tanh(q[t,b,h]+encp[b,e,h]) ----------------
__global__ __launch_bounds__(256) void k_scores(
    const float* qb, const float* encp, const float* vw, float* scores)
{
  int row = blockIdx.x;       // t*64 + b
  int b = row & 63;
  int wave = threadIdx.x >> 6, lane = threadIdx.x & 63;
  float qv[8], vwv[8];
  const float* qr = qb + (long)row * 512 + lane * 8;
  #pragma unroll
  for (int i = 0; i < 8; i++){ qv[i] = qr[i]; vwv[i] = vw[lane * 8 + i]; }
  for (int e = wave; e < 63; e += 4){
    const float* er = encp + (long)(b * 63 + e) * 512 + lane * 8;
    float s = 0.f;
    #pragma unroll
    for (int i = 0; i < 8; i++) s += vwv[i] * tanhf_(qv[i] + er[i]);
    s = wred64(s);
    if (lane == 0) scores[(long)row * 63 + e] = s;
  }
}

// ---------------- softmax over BATCH axis (reference quirk), in-place ----------------
__global__ __launch_bounds__(64) void k_att(float* scores, const unsigned char* mask){
  int idx = blockIdx.x;            // t*63 + e
  int t = idx / 63, e = idx - t * 63;
  int lane = threadIdx.x;          // = b
  long off = (long)(t * 64 + lane) * 63 + e;
  float s = scores[off];
  if (mask[((t + 62) % 63) * 63 + e]) s = NEGV;   // (t-1) mod 63
  float M = wmax64(s);
  float p = __expf(s - M);
  float S = wred64(p);
  scores[off] = p / S;
}

// ---------------- weighted[t,b,h] = sum_e att[t,b,e]*enc[b,e,h] -> feat[:,512:1024] ----------------
__global__ __launch_bounds__(256) void k_weighted(
    const float* att, const float* enc, u16* feat)
{
  int row = blockIdx.x;   // t*64 + b
  int b = row & 63;
  int j = threadIdx.x;
  float a0 = 0.f, a1 = 0.f;
  const float* ar = att + (long)row * 63;
  const float* er = enc + (long)b * 63 * 512;
  for (int e = 0; e < 63; e++){
    float a = ar[e];
    a0 += a * er[(long)e * 512 + j];
    a1 += a * er[(long)e * 512 + j + 256];
  }
  feat[(long)row * 1024 + 512 + j] = f2bf(a0);
  feat[(long)row * 1024 + 768 + j] = f2bf(a1);
}

// ---------------- fc GEMM 128x128 tiles + logsumexp-partial epilogue ----------------
// A = feat (4096,1024) bf16, B = fc_W (32000,1024) bf16. grid (32, 250).
__global__ __launch_bounds__(256) void gemm_fc(
    const u16* Am, const u16* Bm, const float* fcb, float* partials)
{
  __shared__ u16 sA[128 * 32], sB[128 * 32];
  __shared__ float sm[128][2], ss[128][2];
  int tm = blockIdx.x, tn = blockIdx.y;
  int tid = threadIdx.x;
  int wave = tid >> 6, lane = tid & 63;
  int wm = wave >> 1, wn = wave & 1;
  int q = lane >> 4, cl = lane & 15;
  f32x4 acc[4][4];
  #pragma unroll
  for (int i = 0; i < 4; i++)
    #pragma unroll
    for (int j = 0; j < 4; j++) acc[i][j] = (f32x4){0.f, 0.f, 0.f, 0.f};

  const u16 *Ag[2], *Bg[2];
  u16 *sAd[2], *sBd[2];
  #pragma unroll
  for (int h = 0; h < 2; h++){
    int idx = h * 256 + tid, rr = idx >> 2, ck = idx & 3;
    Ag[h] = Am + (long)(tm * 128 + rr) * 1024 + ck * 8;
    Bg[h] = Bm + (long)(tn * 128 + rr) * 1024 + ck * 8;
    // LDS byte offset = idx*16 -> wave-uniform base (h*4+wave)*512 elems + lane*16B
    sAd[h] = &sA[(h * 4 + wave) * 512];
    sBd[h] = &sB[(h * 4 + wave) * 512];
  }
  for (int kt = 0; kt < 1024; kt += 32){
    #pragma unroll
    for (int h = 0; h < 2; h++){
      gl_lds16(Ag[h] + kt, sAd[h]);
      gl_lds16(Bg[h] + kt, sBd[h]);
    }
    __syncthreads();
    bf16x8 afr[4];
    #pragma unroll
    for (int mt = 0; mt < 4; mt++)
      afr[mt] = *(const bf16x8*)&sA[(wm * 64 + mt * 16 + cl) * 32 + q * 8];
    #pragma unroll
    for (int nt = 0; nt < 4; nt++){
      bf16x8 bfv = *(const bf16x8*)&sB[(wn * 64 + nt * 16 + cl) * 32 + q * 8];
      #pragma unroll
      for (int mt = 0; mt < 4; mt++)
        acc[mt][nt] = __builtin_amdgcn_mfma_f32_16x16x32_bf16(afr[mt], bfv, acc[mt][nt], 0, 0, 0);
    }
    __syncthreads();
  }
  float fb[4];
  #pragma unroll
  for (int nt = 0; nt < 4; nt++) fb[nt] = fcb[tn * 128 + wn * 64 + nt * 16 + cl];
  #pragma unroll
  for (int mt = 0; mt < 4; mt++){
    #pragma unroll
    for (int rr = 0; rr < 4; rr++){
      float vals[4];
      float vm = -3.0e38f, vs = 0.f;
      #pragma unroll
      for (int nt = 0; nt < 4; nt++){ float v = acc[mt][nt][rr] + fb[nt]; vals[nt] = v; vm = fmaxf(vm, v); }
      #pragma unroll
      for (int nt = 0; nt < 4; nt++) vs += __expf(vals[nt] - vm);
      #pragma unroll
      for (int m = 1; m < 16; m <<= 1){
        float om = __shfl_xor(vm, m, 16);
        float os = __shfl_xor(vs, m, 16);
        float nm = fmaxf(vm, om);
        vs = vs * __expf(vm - nm) + os * __expf(om - nm);
        vm = nm;
      }
      if (cl == 0){ int rl = wm * 64 + mt * 16 + q * 4 + rr; sm[rl][wn] = vm; ss[rl][wn] = vs; }
    }
  }
  __syncthreads();
  if (tid < 128){
    float m0 = sm[tid][0], m1 = sm[tid][1];
    float M = fmaxf(m0, m1);
    float S = ss[tid][0] * __expf(m0 - M) + ss[tid][1] * __expf(m1 - M);
    long row = tm * 128 + tid;
    partials[(row * 250 + tn) * 2]     = M;
    partials[(row * 250 + tn) * 2 + 1] = S;
  }
}

// ---------------- per-row logsumexp combine + target logit -> nll ----------------
__global__ __launch_bounds__(256) void k_rowstats(
    const float* partials, const u16* feat, const u16* fcwb,
    const float* fcb, const int* X, float* nll)
{
  int row = blockIdx.x * 4 + (threadIdx.x >> 6);
  int lane = threadIdx.x & 63;
  if (row >= 4032) return;
  float vm = -3.0e38f, vs = 0.f;
  const float* pr = partials + (long)row * 500;
  for (int i = lane; i < 250; i += 64){
    float m = pr[i * 2], s2 = pr[i * 2 + 1];
    float nm = fmaxf(vm, m);
    vs = vs * __expf(vm - nm) + s2 * __expf(m - nm);
    vm = nm;
  }
  #pragma unroll
  for (int m = 32; m; m >>= 1){
    float om = __shfl_xor(vm, m, 64);
    float os = __shfl_xor(vs, m, 64);
    float nm = fmaxf(vm, om);
    vs = vs * __expf(vm - nm) + os * __expf(om - nm);
    vm = nm;
  }
  float logZ = vm + __logf(vs);
  int t = row >> 6, b = row & 63;
  int tgt = X[b * 64 + t + 1];
  const u16* fr = feat + (long)row * 1024 + lane * 16;
  const u16* wr = fcwb + (long)tgt * 1024 + lane * 16;
  float d = 0.f;
  #pragma unroll
  for (int i = 0; i < 16; i++) d += bf2f(fr[i]) * bf2f(wr[i]);
  d = wred64(d);
  if (lane == 0) nll[row] = logZ - (d + fcb[tgt]);
}

// ---------------- final masked mean ----------------
__global__ __launch_bounds__(256) void k_final(const float* nll, const int* X, float* out){
  __shared__ float lt[64];
  int wave = threadIdx.x >> 6, lane = threadIdx.x & 63;
  for (int t = wave; t < 63; t += 4){
    int tgt = X[lane * 64 + t + 1];
    float v = (tgt != 0) ? nll[t * 64 + lane] : 0.f;
    float c = (tgt != 0) ? 1.f : 0.f;
    v = wred64(v); c = wred64(c);
    if (lane == 0) lt[t] = v / c;
  }
  __syncthreads();
  if (threadIdx.x == 0){
    float s = 0.f;
    for (int t = 0; t < 63; t++) s += lt[t];
    out[0] = s / 63.f;
  }
}

extern "C" void kernel_launch(void* const* d_in, const int* in_sizes, int n_in,
                              void* d_out, int out_size, void* d_ws, size_t ws_size,
                              hipStream_t stream)
{
  (void)in_sizes; (void)n_in; (void)out_size; (void)ws_size;
  const int*   X    = (const int*)d_in[0];
  const float* enc  = (const float*)d_in[1];
  const unsigned char* mask = (const unsigned char*)d_in[2];
  const float* emb  = (const float*)d_in[3];
  const float* wih  = (const float*)d_in[4];
  const float* whh  = (const float*)d_in[5];
  const float* bih  = (const float*)d_in[6];
  const float* bhh  = (const float*)d_in[7];
  const float* awh  = (const float*)d_in[8];
  const float* awe  = (const float*)d_in[9];
  const float* ab   = (const float*)d_in[10];
  const float* vw   = (const float*)d_in[11];
  const float* fcw  = (const float*)d_in[12];
  const float* fcb  = (const float*)d_in[13];
  float* out = (float*)d_out;

  char* w = (char*)d_ws;
  size_t o = 0;
  auto alloc = [&](size_t bytes){ size_t r = o; o = (o + bytes + 255) & ~(size_t)255; return r; };
  size_t o_ebf  = alloc((size_t)4032 * 512 * 2);
  size_t o_wihb = alloc((size_t)2 * 2048 * 512 * 2);
  size_t o_whhb = alloc((size_t)2 * 2048 * 512 * 2);
  size_t o_web  = alloc((size_t)512 * 512 * 2);
  size_t o_whb  = alloc((size_t)512 * 512 * 2);
  size_t o_fcwb = alloc((size_t)32000 * 1024 * 2);
  size_t o_encb = alloc((size_t)4032 * 512 * 2);
  size_t o_b01  = alloc((size_t)4096 * 4);
  size_t o_x0   = alloc((size_t)4032 * 2048 * 2);        // bf16
  size_t o_encp = alloc((size_t)4032 * 512 * 4);
  size_t o_q    = alloc((size_t)4032 * 512 * 4);
  size_t o_feat = alloc((size_t)4096 * 1024 * 2);
  size_t o_ring = alloc((size_t)2 * 8 * 32768 * 2);      // ring0 + ring1 (depth 8)
  size_t o_done = alloc((size_t)256);                    // done[64] tick counters
  size_t o_sc   = alloc((size_t)63 * 64 * 63 * 4);
  size_t o_part = alloc((size_t)4096 * 250 * 2 * 4);
  size_t o_nll  = alloc((size_t)4032 * 4);

  u16* ebf   = (u16*)(w + o_ebf);
  u16* wihb  = (u16*)(w + o_wihb);
  u16* whhb  = (u16*)(w + o_whhb);
  u16* web   = (u16*)(w + o_web);
  u16* whb   = (u16*)(w + o_whb);
  u16* fcwb  = (u16*)(w + o_fcwb);
  u16* encb  = (u16*)(w + o_encb);
  float* b01 = (float*)(w + o_b01);
  u16* x0b   = (u16*)(w + o_x0);
  float* encp= (float*)(w + o_encp);
  float* qb  = (float*)(w + o_q);
  u16* feat  = (u16*)(w + o_feat);
  u16* ring0 = (u16*)(w + o_ring);
  u16* ring1 = ring0 + 8 * 32768;
  int* done  = (int*)(w + o_done);
  float* sc  = (float*)(w + o_sc);
  float* part= (float*)(w + o_part);
  float* nllb= (float*)(w + o_nll);

  // zero rings + done counters (contiguous)
  hipMemsetAsync(w + o_ring, 0, (o_done - o_ring) + 256, stream);

  k_prep<<<4096, 256, 0, stream>>>(wih, whh, awe, awh, fcw, enc, bih, bhh,
                                   wihb, whhb, web, whb, fcwb, encb, b01);
  k_embed<<<4032, 256, 0, stream>>>(X, emb, ebf);

  // X0 = E @ Wih0^T + (bih0+bhh0): (4032,2048) K=512, bf16 output
  gemm_btb<<<dim3(63, 32), 256, 0, stream>>>(ebf, 512, wihb, 512, x0b, 2048, b01, 512);
  // enc_proj = enc @ We^T + attn_b: (4032,512) K=512 (rows b*63+e)
  gemm_bt<<<dim3(63, 8), 256, 0, stream>>>(encb, 512, web, 512, encp, 512, ab, 512);

  // merged 2-layer pipelined LSTM: 32 WGs, one rendezvous per tick
  lstm_pipe<<<32, 256, 0, stream>>>(whhb, wihb + 2048 * 512, whhb + 2048 * 512,
                                    x0b, b01 + 2048, ring0, ring1, feat, done);

  // q = top @ Wh^T: A = feat[:, :512] (lda=1024)
  gemm_bt<<<dim3(63, 8), 256, 0, stream>>>(feat, 1024, whb, 512, qb, 512, nullptr, 512);
  k_scores<<<4032, 256, 0, stream>>>(qb, encp, vw, sc);
  k_att<<<3969, 64, 0, stream>>>(sc, mask);
  k_weighted<<<4032, 256, 0, stream>>>(sc, enc, feat);

  gemm_fc<<<dim3(32, 250), 256, 0, stream>>>(feat, fcwb, fcb, part);
  k_rowstats<<<1008, 256, 0, stream>>>(part, feat, fcwb, fcb, X, nllb);
  k_final<<<1, 256, 0, stream>>>(nllb, X, out);
}

// Round 6
// 1329.078 us; speedup vs baseline: 1.3684x; 1.3684x over previous
//
#include <hip/hip_runtime.h>
#include <math.h>

// Problem constants: V=32000 D=512 H=512 L=2 B=64 S=64 -> T=Te=63
#define NEGV -1000000000.0f

typedef unsigned short u16;
typedef __attribute__((ext_vector_type(8))) short bf16x8;
typedef __attribute__((ext_vector_type(4))) float f32x4;

__device__ __forceinline__ u16 f2bf(float f){
  union { float f; unsigned u; } v; v.f = f;
  unsigned u = v.u;
  unsigned r = (u + 0x7fffu + ((u >> 16) & 1u)) >> 16;
  return (u16)r;
}
__device__ __forceinline__ float bf2f(u16 b){
  union { unsigned u; float f; } v; v.u = ((unsigned)b) << 16;
  return v.f;
}
__device__ __forceinline__ float sigmf(float x){ return 1.f / (1.f + __expf(-x)); }
__device__ __forceinline__ float tanhf_(float x){
  float e = __expf(-2.f * fabsf(x));
  float t = (1.f - e) / (1.f + e);
  return x >= 0.f ? t : -t;
}
__device__ __forceinline__ float wred64(float v){
  #pragma unroll
  for (int m = 32; m; m >>= 1) v += __shfl_xor(v, m, 64);
  return v;
}
__device__ __forceinline__ float wmax64(float v){
  #pragma unroll
  for (int m = 32; m; m >>= 1) v = fmaxf(v, __shfl_xor(v, m, 64));
  return v;
}

// ---- async global->LDS (16B/lane). LDS dest is wave-uniform base + lane*16. ----
typedef const __attribute__((address_space(1))) unsigned int* gas_ptr;
typedef __attribute__((address_space(3))) unsigned int* las_ptr;
__device__ __forceinline__ void gl_lds16(const u16* g, u16* l){
  __builtin_amdgcn_global_load_lds((gas_ptr)g, (las_ptr)l, 16, 0, 0);
}

// ---- agent-scope (sc1) write-through 2B store: h-ring data bypasses L1/L2 ----
__device__ __forceinline__ void st_sc1_u16(u16* p, unsigned v){
  asm volatile("global_store_short %0, %1, off sc1" :: "v"(p), "v"(v) : "memory");
}

// ---------------- prep: fp32 -> bf16 weight copies + bias sums ----------------
__global__ __launch_bounds__(256) void k_prep(
    const float* wih, const float* whh, const float* we, const float* wh,
    const float* fcw, const float* enc, const float* bih, const float* bhh,
    u16* wihb, u16* whhb, u16* web, u16* whb, u16* fcwb, u16* encb, float* b01)
{
  const long n0 = 2097152, n1 = 2097152, n2 = 262144, n3 = 262144;
  const long n4 = 32768000, n5 = 2064384, n6 = 4096;
  const long total = n0 + n1 + n2 + n3 + n4 + n5 + n6;
  long stride = (long)gridDim.x * 256;
  for (long i = (long)blockIdx.x * 256 + threadIdx.x; i < total; i += stride){
    long j = i;
    if (j < n0){ wihb[j] = f2bf(wih[j]); continue; } j -= n0;
    if (j < n1){ whhb[j] = f2bf(whh[j]); continue; } j -= n1;
    if (j < n2){ web[j]  = f2bf(we[j]);  continue; } j -= n2;
    if (j < n3){ whb[j]  = f2bf(wh[j]);  continue; } j -= n3;
    if (j < n4){ fcwb[j] = f2bf(fcw[j]); continue; } j -= n4;
    if (j < n5){ encb[j] = f2bf(enc[j]); continue; } j -= n5;
    b01[j] = bih[j] + bhh[j];   // j<2048: layer0 bias sum; 2048..4095: layer1
  }
}

// ---------------- embedding gather -> bf16 ----------------
__global__ __launch_bounds__(256) void k_embed(const int* X, const float* emb, u16* ebf){
  int row = blockIdx.x;            // t*64 + b
  int t = row >> 6, b = row & 63;
  int tok = X[b * 64 + t];         // X is (B=64, S=64)
  const float* src = emb + (long)tok * 512;
  u16* dst = ebf + (long)row * 512;
  for (int j = threadIdx.x; j < 512; j += 256) dst[j] = f2bf(src[j]);
}

// ---------------- generic bf16 GEMM: C(M,N) = A(M,K) @ B(N,K)^T + bias (fp32 out) ----------------
__global__ __launch_bounds__(256) void gemm_bt(
    const u16* Am, int lda, const u16* Bm, int ldb,
    float* C, int ldc, const float* bias, int K)
{
  __shared__ u16 sA[64 * 32], sB[64 * 32];
  int tm = blockIdx.x, tn = blockIdx.y;
  int tid = threadIdx.x;
  int wave = tid >> 6, lane = tid & 63;
  int wm = wave >> 1, wn = wave & 1;
  int q = lane >> 4, cl = lane & 15;
  f32x4 acc[2][2];
  #pragma unroll
  for (int i = 0; i < 2; i++)
    #pragma unroll
    for (int j = 0; j < 2; j++) acc[i][j] = (f32x4){0.f, 0.f, 0.f, 0.f};

  int r = tid >> 2, ck = tid & 3;
  const u16* Ags = Am + (long)(tm * 64 + r) * lda + ck * 8;
  const u16* Bgs = Bm + (long)(tn * 64 + r) * ldb + ck * 8;
  // LDS layout is linear in tid (byte off = tid*16) -> direct global_load_lds
  u16* sAw = &sA[wave * 512];
  u16* sBw = &sB[wave * 512];

  for (int kt = 0; kt < K; kt += 32){
    gl_lds16(Ags + kt, sAw);
    gl_lds16(Bgs + kt, sBw);
    __syncthreads();
    #pragma unroll
    for (int i = 0; i < 2; i++){
      bf16x8 af = *(const bf16x8*)&sA[(wm * 32 + i * 16 + cl) * 32 + q * 8];
      #pragma unroll
      for (int j = 0; j < 2; j++){
        bf16x8 bfv = *(const bf16x8*)&sB[(wn * 32 + j * 16 + cl) * 32 + q * 8];
        acc[i][j] = __builtin_amdgcn_mfma_f32_16x16x32_bf16(af, bfv, acc[i][j], 0, 0, 0);
      }
    }
    __syncthreads();
  }
  #pragma unroll
  for (int i = 0; i < 2; i++)
    #pragma unroll
    for (int j = 0; j < 2; j++){
      int colg = tn * 64 + wn * 32 + j * 16 + cl;
      float bv = bias ? bias[colg] : 0.f;
      #pragma unroll
      for (int rr = 0; rr < 4; rr++){
        int rowg = tm * 64 + wm * 32 + i * 16 + q * 4 + rr;
        C[(long)rowg * ldc + colg] = acc[i][j][rr] + bv;
      }
    }
}

// ---------------- same GEMM but bf16 output (for x0 gate pre-activations) ----------------
__global__ __launch_bounds__(256) void gemm_btb(
    const u16* Am, int lda, const u16* Bm, int ldb,
    u16* C, int ldc, const float* bias, int K)
{
  __shared__ u16 sA[64 * 32], sB[64 * 32];
  int tm = blockIdx.x, tn = blockIdx.y;
  int tid = threadIdx.x;
  int wave = tid >> 6, lane = tid & 63;
  int wm = wave >> 1, wn = wave & 1;
  int q = lane >> 4, cl = lane & 15;
  f32x4 acc[2][2];
  #pragma unroll
  for (int i = 0; i < 2; i++)
    #pragma unroll
    for (int j = 0; j < 2; j++) acc[i][j] = (f32x4){0.f, 0.f, 0.f, 0.f};

  int r = tid >> 2, ck = tid & 3;
  const u16* Ags = Am + (long)(tm * 64 + r) * lda + ck * 8;
  const u16* Bgs = Bm + (long)(tn * 64 + r) * ldb + ck * 8;
  u16* sAw = &sA[wave * 512];
  u16* sBw = &sB[wave * 512];

  for (int kt = 0; kt < K; kt += 32){
    gl_lds16(Ags + kt, sAw);
    gl_lds16(Bgs + kt, sBw);
    __syncthreads();
    #pragma unroll
    for (int i = 0; i < 2; i++){
      bf16x8 af = *(const bf16x8*)&sA[(wm * 32 + i * 16 + cl) * 32 + q * 8];
      #pragma unroll
      for (int j = 0; j < 2; j++){
        bf16x8 bfv = *(const bf16x8*)&sB[(wn * 32 + j * 16 + cl) * 32 + q * 8];
        acc[i][j] = __builtin_amdgcn_mfma_f32_16x16x32_bf16(af, bfv, acc[i][j], 0, 0, 0);
      }
    }
    __syncthreads();
  }
  #pragma unroll
  for (int i = 0; i < 2; i++)
    #pragma unroll
    for (int j = 0; j < 2; j++){
      int colg = tn * 64 + wn * 32 + j * 16 + cl;
      float bv = bias ? bias[colg] : 0.f;
      #pragma unroll
      for (int rr = 0; rr < 4; rr++){
        int rowg = tm * 64 + wm * 32 + i * 16 + q * 4 + rr;
        C[(long)rowg * ldc + colg] = f2bf(acc[i][j][rr] + bv);
      }
    }
}

// ---------------- pipelined LSTM (R3 topology): 64 WGs, layer-pipelined ----------------
// done0[t] / done1[t]: count of layer-0 / layer-1 WGs that completed tick t.
// Waiters poll ONE shared word per condition (lane<32 -> cond0, lane>=32 -> cond1);
// 32 lanes on the same address coalesce to a single MALL request per poll iter.
//   L0 @ t: done0[t-1]==32 (h0(t-1) full) && done1[t-8]==32 (ring0 slot reuse, rarely binds)
//   L1 @ t: done0[t]==32 (h0(t) full)     && done1[t-1]==32 (h1(t-1) full)
// h rings depth 8, slot t&7; slot 7 zero-init serves t=-1.
// Coherence: sc1 write-through stores + sc1 direct loads; no wbl2/inv anywhere.
__device__ __forceinline__ void wait_cnt2(const int* p0, const int* p1, int tid){
  if (tid < 64){
    const int* p = (tid < 32) ? p0 : p1;
    for (;;){
      int v = p ? __hip_atomic_load(p, __ATOMIC_RELAXED, __HIP_MEMORY_SCOPE_AGENT)
                : 32;
      if (__ballot(v >= 32) == ~0ull) break;
    }
  }
  __syncthreads();
}

// issue 16 sc1 b128 loads (one K-pass of A-fragments), no wait
#define ISSUE_RING_FRAGS(afr, Ab)                                              \
  {                                                                            \
    _Pragma("unroll")                                                          \
    for (int kt = 0; kt < 16; kt++)                                            \
      asm volatile("global_load_dwordx4 %0, %1, off offset:%2 sc1"             \
                   : "=v"(afr[kt]) : "v"(Ab), "i"(kt * 64));                   \
  }
#define WAITCNT_VM(N)                                                          \
  { asm volatile("s_waitcnt vmcnt(" #N ")" ::: "memory");                      \
    __builtin_amdgcn_sched_barrier(0); }

__global__ __launch_bounds__(256, 1) void lstm_pipe(
    const u16* whh0, const u16* wih1, const u16* whh1,
    const u16* x0b, const float* b1s,
    u16* ring0, u16* ring1, u16* feat, int* done)
{
  __shared__ u16 sW[32768];    // layer0: Whh0 slice; layer1: Whh1 slice (recurrent B)
  __shared__ u16 sW2[32768];   // layer1 only: Wih1 slice (input-term B)
  int* done0 = done;
  int* done1 = done + 64;
  int wg = blockIdx.x;
  int layer = wg >> 5;
  int cc = (wg & 31) * 16;
  int tid = threadIdx.x;
  int wave = tid >> 6, lane = tid & 63;
  int q = lane >> 4, cl = lane & 15;
  int j = cc + cl;

  // one-time weight stage (fragment-contiguous: unit (kt*4+q)*4+g holds 16 rows x 8 elems)
  {
    const u16* src = layer ? whh1 : whh0;
    for (int ch = tid; ch < 4096; ch += 256){
      int row = ch >> 6, c = ch & 63;
      int g = row >> 4, r = row & 15;
      *(uint4*)&sW[((c * 4 + g) * 16 + r) * 8] =
          *(const uint4*)&src[(long)(g * 512 + cc + r) * 512 + c * 8];
      if (layer)
        *(uint4*)&sW2[((c * 4 + g) * 16 + r) * 8] =
            *(const uint4*)&wih1[(long)(g * 512 + cc + r) * 512 + c * 8];
    }
  }
  __syncthreads();

  float cst[4] = {0.f, 0.f, 0.f, 0.f};   // register-resident c-state slice
  float bg[4];
  if (layer){
    #pragma unroll
    for (int g = 0; g < 4; g++) bg[g] = b1s[g * 512 + j];
  }

  int foff = (wave * 16 + cl) * 512 + q * 8;   // per-thread A-fragment offset in a slot

  for (int t = 0; t < 63; t++){
    f32x4 acc[4];
    #pragma unroll
    for (int g = 0; g < 4; g++) acc[g] = (f32x4){0.f, 0.f, 0.f, 0.f};

    if (layer == 0){
      // prefetch x0 gate slice (static data, cached) BEFORE the wait
      float xg[4][4];
      #pragma unroll
      for (int rr = 0; rr < 4; rr++){
        int s = wave * 16 + q * 4 + rr;
        const u16* xr = x0b + (long)(t * 64 + s) * 2048 + j;
        #pragma unroll
        for (int g = 0; g < 4; g++) xg[g][rr] = bf2f(xr[g * 512]);
      }
      // single rendezvous: h0(t-1) complete; slot back-pressure (rarely binds)
      wait_cnt2(t > 0 ? done0 + (t - 1) : nullptr,
                t >= 8 ? done1 + (t - 8) : nullptr, tid);
      {
        const u16* Ab = ring0 + ((t + 7) & 7) * 32768 + foff;
        bf16x8 afr[16];
        ISSUE_RING_FRAGS(afr, Ab);
        WAITCNT_VM(0);
        #pragma unroll
        for (int kt = 0; kt < 16; kt++)
          #pragma unroll
          for (int g = 0; g < 4; g++){
            bf16x8 bfv = *(const bf16x8*)&sW[(((kt * 4 + q) * 4 + g) * 16 + cl) * 8];
            acc[g] = __builtin_amdgcn_mfma_f32_16x16x32_bf16(afr[kt], bfv, acc[g], 0, 0, 0);
          }
      }
      u16* hn = ring0 + (t & 7) * 32768;
      #pragma unroll
      for (int rr = 0; rr < 4; rr++){
        int s = wave * 16 + q * 4 + rr;
        float gi = acc[0][rr] + xg[0][rr];
        float gf = acc[1][rr] + xg[1][rr];
        float gg = acc[2][rr] + xg[2][rr];
        float go = acc[3][rr] + xg[3][rr];
        float cn = sigmf(gf) * cst[rr] + sigmf(gi) * tanhf_(gg);
        cst[rr] = cn;
        st_sc1_u16(hn + s * 512 + j, (unsigned)f2bf(sigmf(go) * tanhf_(cn)));
      }
    } else {
      // SINGLE combined rendezvous: h0(t) ready AND h1(t-1) ready
      wait_cnt2(done0 + t, t > 0 ? done1 + (t - 1) : nullptr, tid);
      const u16* Ab1 = ring1 + ((t + 7) & 7) * 32768 + foff;   // h1(t-1)
      const u16* Ab0 = ring0 + (t & 7) * 32768 + foff;         // h0(t)
      bf16x8 a1[16], a0[16];
      ISSUE_RING_FRAGS(a1, Ab1);
      ISSUE_RING_FRAGS(a0, Ab0);
      WAITCNT_VM(16);                     // a1 landed; a0 still in flight
      #pragma unroll
      for (int kt = 0; kt < 16; kt++)
        #pragma unroll
        for (int g = 0; g < 4; g++){
          bf16x8 bfv = *(const bf16x8*)&sW[(((kt * 4 + q) * 4 + g) * 16 + cl) * 8];
          acc[g] = __builtin_amdgcn_mfma_f32_16x16x32_bf16(a1[kt], bfv, acc[g], 0, 0, 0);
        }
      WAITCNT_VM(0);                      // a0 landed (mostly hidden under pass A)
      #pragma unroll
      for (int kt = 0; kt < 16; kt++)
        #pragma unroll
        for (int g = 0; g < 4; g++){
          bf16x8 bfv = *(const bf16x8*)&sW2[(((kt * 4 + q) * 4 + g) * 16 + cl) * 8];
          acc[g] = __builtin_amdgcn_mfma_f32_16x16x32_bf16(a0[kt], bfv, acc[g], 0, 0, 0);
        }
      u16* hn = ring1 + (t & 7) * 32768;
      #pragma unroll
      for (int rr = 0; rr < 4; rr++){
        int s = wave * 16 + q * 4 + rr;
        float gi = acc[0][rr] + bg[0];
        float gf = acc[1][rr] + bg[1];
        float gg = acc[2][rr] + bg[2];
        float go = acc[3][rr] + bg[3];
        float cn = sigmf(gf) * cst[rr] + sigmf(gi) * tanhf_(gg);
        cst[rr] = cn;
        u16 hb = f2bf(sigmf(go) * tanhf_(cn));
        st_sc1_u16(hn + s * 512 + j, (unsigned)hb);
        feat[(long)(t * 64 + s) * 1024 + j] = hb;   // top_t (normal store, post-kernel use)
      }
    }
    // drain ALL stores (incl. inline-asm sc1 stores the compiler doesn't track)
    asm volatile("s_waitcnt vmcnt(0)" ::: "memory");
    __syncthreads();
    if (tid == 0)
      (void)__hip_atomic_fetch_add((layer ? done1 : done0) + t, 1,
                                   __ATOMIC_RELAXED, __HIP_MEMORY_SCOPE_AGENT);
  }
}

// ---------------- attention scores: s[t,b,e] = sum_h vw[h]*tanh(q[t,b,h]+encp[b,e,h]) ----------------
__global__ __launch_bounds__(256) void k_scores(
    const float* qb, const float* encp, const float* vw, float* scores)
{
  int row = blockIdx.x;       // t*64 + b
  int b = row & 63;
  int wave = threadIdx.x >> 6, lane = threadIdx.x & 63;
  float qv[8], vwv[8];
  const float* qr = qb + (long)row * 512 + lane * 8;
  #pragma unroll
  for (int i = 0; i < 8; i++){ qv[i] = qr[i]; vwv[i] = vw[lane * 8 + i]; }
  for (int e = wave; e < 63; e += 4){
    const float* er = encp + (long)(b * 63 + e) * 512 + lane * 8;
    float s = 0.f;
    #pragma unroll
    for (int i = 0; i < 8; i++) s += vwv[i] * tanhf_(qv[i] + er[i]);
    s = wred64(s);
    if (lane == 0) scores[(long)row * 63 + e] = s;
  }
}

// ---------------- softmax over BATCH axis (reference quirk), in-place ----------------
__global__ __launch_bounds__(64) void k_att(float* scores, const unsigned char* mask){
  int idx = blockIdx.x;            // t*63 + e
  int t = idx / 63, e = idx - t * 63;
  int lane = threadIdx.x;          // = b
  long off = (long)(t * 64 + lane) * 63 + e;
  float s = scores[off];
  if (mask[((t + 62) % 63) * 63 + e]) s = NEGV;   // (t-1) mod 63
  float M = wmax64(s);
  float p = __expf(s - M);
  float S = wred64(p);
  scores[off] = p / S;
}

// ---------------- weighted[t,b,h] = sum_e att[t,b,e]*enc[b,e,h] -> feat[:,512:1024] ----------------
__global__ __launch_bounds__(256) void k_weighted(
    const float* att, const float* enc, u16* feat)
{
  int row = blockIdx.x;   // t*64 + b
  int b = row & 63;
  int j = threadIdx.x;
  float a0 = 0.f, a1 = 0.f;
  const float* ar = att + (long)row * 63;
  const float* er = enc + (long)b * 63 * 512;
  for (int e = 0; e < 63; e++){
    float a = ar[e];
    a0 += a * er[(long)e * 512 + j];
    a1 += a * er[(long)e * 512 + j + 256];
  }
  feat[(long)row * 1024 + 512 + j] = f2bf(a0);
  feat[(long)row * 1024 + 768 + j] = f2bf(a1);
}

// ---------------- fc GEMM 128x128 tiles, 2-phase double-buffered staging ----------------
// A = feat (4096,1024) bf16, B = fc_W (32000,1024) bf16. grid (32, 250).
// Per K-iter: issue next tile's global_load_lds into buf^1 BEFORE computing buf;
// single barrier per iter (implicit vmcnt(0) drains the in-flight stage).
__global__ __launch_bounds__(256) void gemm_fc(
    const u16* Am, const u16* Bm, const float* fcb, float* partials)
{
  __shared__ u16 sA[2][128 * 32], sB[2][128 * 32];
  __shared__ float sm[128][2], ss[128][2];
  int tm = blockIdx.x, tn = blockIdx.y;
  int tid = threadIdx.x;
  int wave = tid >> 6, lane = tid & 63;
  int wm = wave >> 1, wn = wave & 1;
  int q = lane >> 4, cl = lane & 15;
  f32x4 acc[4][4];
  #pragma unroll
  for (int i = 0; i < 4; i++)
    #pragma unroll
    for (int j = 0; j < 4; j++) acc[i][j] = (f32x4){0.f, 0.f, 0.f, 0.f};

  const u16 *Ag[2], *Bg[2];
  int sOff[2];
  #pragma unroll
  for (int h = 0; h < 2; h++){
    int idx = h * 256 + tid, rr = idx >> 2, ck = idx & 3;
    Ag[h] = Am + (long)(tm * 128 + rr) * 1024 + ck * 8;
    Bg[h] = Bm + (long)(tn * 128 + rr) * 1024 + ck * 8;
    // LDS byte offset = idx*16 -> wave-uniform base (h*4+wave)*512 elems + lane*16B
    sOff[h] = (h * 4 + wave) * 512;
  }
  // prologue: stage K-tile 0 into buf 0
  #pragma unroll
  for (int h = 0; h < 2; h++){
    gl_lds16(Ag[h], &sA[0][sOff[h]]);
    gl_lds16(Bg[h], &sB[0][sOff[h]]);
  }
  __syncthreads();
  int cur = 0;
  for (int kt = 0; kt < 1024; kt += 32){
    if (kt + 32 < 1024){
      #pragma unroll
      for (int h = 0; h < 2; h++){
        gl_lds16(Ag[h] + kt + 32, &sA[cur ^ 1][sOff[h]]);
        gl_lds16(Bg[h] + kt + 32, &sB[cur ^ 1][sOff[h]]);
      }
    }
    bf16x8 afr[4];
    #pragma unroll
    for (int mt = 0; mt < 4; mt++)
      afr[mt] = *(const bf16x8*)&sA[cur][(wm * 64 + mt * 16 + cl) * 32 + q * 8];
    #pragma unroll
    for (int nt = 0; nt < 4; nt++){
      bf16x8 bfv = *(const bf16x8*)&sB[cur][(wn * 64 + nt * 16 + cl) * 32 + q * 8];
      #pragma unroll
      for (int mt = 0; mt < 4; mt++)
        acc[mt][nt] = __builtin_amdgcn_mfma_f32_16x16x32_bf16(afr[mt], bfv, acc[mt][nt], 0, 0, 0);
    }
    __syncthreads();   // drains in-flight stage (implicit vmcnt 0) + protects buf reuse
    cur ^= 1;
  }
  float fb[4];
  #pragma unroll
  for (int nt = 0; nt < 4; nt++) fb[nt] = fcb[tn * 128 + wn * 64 + nt * 16 + cl];
  #pragma unroll
  for (int mt = 0; mt < 4; mt++){
    #pragma unroll
    for (int rr = 0; rr < 4; rr++){
      float vals[4];
      float vm = -3.0e38f, vs = 0.f;
      #pragma unroll
      for (int nt = 0; nt < 4; nt++){ float v = acc[mt][nt][rr] + fb[nt]; vals[nt] = v; vm = fmaxf(vm, v); }
      #pragma unroll
      for (int nt = 0; nt < 4; nt++) vs += __expf(vals[nt] - vm);
      #pragma unroll
      for (int m = 1; m < 16; m <<= 1){
        float om = __shfl_xor(vm, m, 16);
        float os = __shfl_xor(vs, m, 16);
        float nm = fmaxf(vm, om);
        vs = vs * __expf(vm - nm) + os * __expf(om - nm);
        vm = nm;
      }
      if (cl == 0){ int rl = wm * 64 + mt * 16 + q * 4 + rr; sm[rl][wn] = vm; ss[rl][wn] = vs; }
    }
  }
  __syncthreads();
  if (tid < 128){
    float m0 = sm[tid][0], m1 = sm[tid][1];
    float M = fmaxf(m0, m1);
    float S = ss[tid][0] * __expf(m0 - M) + ss[tid][1] * __expf(m1 - M);
    long row = tm * 128 + tid;
    partials[(row * 250 + tn) * 2]     = M;
    partials[(row * 250 + tn) * 2 + 1] = S;
  }
}

// ---------------- per-row logsumexp combine + target logit -> nll ----------------
__global__ __launch_bounds__(256) void k_rowstats(
    const float* partials, const u16* feat, const u16* fcwb,
    const float* fcb, const int* X, float* nll)
{
  int row = blockIdx.x * 4 + (threadIdx.x >> 6);
  int lane = threadIdx.x & 63;
  if (row >= 4032) return;
  float vm = -3.0e38f, vs = 0.f;
  const float* pr = partials + (long)row * 500;
  for (int i = lane; i < 250; i += 64){
    float m = pr[i * 2], s2 = pr[i * 2 + 1];
    float nm = fmaxf(vm, m);
    vs = vs * __expf(vm - nm) + s2 * __expf(m - nm);
    vm = nm;
  }
  #pragma unroll
  for (int m = 32; m; m >>= 1){
    float om = __shfl_xor(vm, m, 64);
    float os = __shfl_xor(vs, m, 64);
    float nm = fmaxf(vm, om);
    vs = vs * __expf(vm - nm) + os * __expf(om - nm);
    vm = nm;
  }
  float logZ = vm + __logf(vs);
  int t = row >> 6, b = row & 63;
  int tgt = X[b * 64 + t + 1];
  const u16* fr = feat + (long)row * 1024 + lane * 16;
  const u16* wr = fcwb + (long)tgt * 1024 + lane * 16;
  float d = 0.f;
  #pragma unroll
  for (int i = 0; i < 16; i++) d += bf2f(fr[i]) * bf2f(wr[i]);
  d = wred64(d);
  if (lane == 0) nll[row] = logZ - (d + fcb[tgt]);
}

// ---------------- final masked mean ----------------
__global__ __launch_bounds__(256) void k_final(const float* nll, const int* X, float* out){
  __shared__ float lt[64];
  int wave = threadIdx.x >> 6, lane = threadIdx.x & 63;
  for (int t = wave; t < 63; t += 4){
    int tgt = X[lane * 64 + t + 1];
    float v = (tgt != 0) ? nll[t * 64 + lane] : 0.f;
    float c = (tgt != 0) ? 1.f : 0.f;
    v = wred64(v); c = wred64(c);
    if (lane == 0) lt[t] = v / c;
  }
  __syncthreads();
  if (threadIdx.x == 0){
    float s = 0.f;
    for (int t = 0; t < 63; t++) s += lt[t];
    out[0] = s / 63.f;
  }
}

extern "C" void kernel_launch(void* const* d_in, const int* in_sizes, int n_in,
                              void* d_out, int out_size, void* d_ws, size_t ws_size,
                              hipStream_t stream)
{
  (void)in_sizes; (void)n_in; (void)out_size; (void)ws_size;
  const int*   X    = (const int*)d_in[0];
  const float* enc  = (const float*)d_in[1];
  const unsigned char* mask = (const unsigned char*)d_in[2];
  const float* emb  = (const float*)d_in[3];
  const float* wih  = (const float*)d_in[4];
  const float* whh  = (const float*)d_in[5];
  const float* bih  = (const float*)d_in[6];
  const float* bhh  = (const float*)d_in[7];
  const float* awh  = (const float*)d_in[8];
  const float* awe  = (const float*)d_in[9];
  const float* ab   = (const float*)d_in[10];
  const float* vw   = (const float*)d_in[11];
  const float* fcw  = (const float*)d_in[12];
  const float* fcb  = (const float*)d_in[13];
  float* out = (float*)d_out;

  char* w = (char*)d_ws;
  size_t o = 0;
  auto alloc = [&](size_t bytes){ size_t r = o; o = (o + bytes + 255) & ~(size_t)255; return r; };
  size_t o_ebf  = alloc((size_t)4032 * 512 * 2);
  size_t o_wihb = alloc((size_t)2 * 2048 * 512 * 2);
  size_t o_whhb = alloc((size_t)2 * 2048 * 512 * 2);
  size_t o_web  = alloc((size_t)512 * 512 * 2);
  size_t o_whb  = alloc((size_t)512 * 512 * 2);
  size_t o_fcwb = alloc((size_t)32000 * 1024 * 2);
  size_t o_encb = alloc((size_t)4032 * 512 * 2);
  size_t o_b01  = alloc((size_t)4096 * 4);
  size_t o_x0   = alloc((size_t)4032 * 2048 * 2);        // bf16
  size_t o_encp = alloc((size_t)4032 * 512 * 4);
  size_t o_q    = alloc((size_t)4032 * 512 * 4);
  size_t o_feat = alloc((size_t)4096 * 1024 * 2);
  size_t o_ring = alloc((size_t)2 * 8 * 32768 * 2);      // ring0 + ring1 (depth 8)
  size_t o_done = alloc((size_t)512);                    // done0[64] + done1[64]
  size_t o_sc   = alloc((size_t)63 * 64 * 63 * 4);
  size_t o_part = alloc((size_t)4096 * 250 * 2 * 4);
  size_t o_nll  = alloc((size_t)4032 * 4);

  u16* ebf   = (u16*)(w + o_ebf);
  u16* wihb  = (u16*)(w + o_wihb);
  u16* whhb  = (u16*)(w + o_whhb);
  u16* web   = (u16*)(w + o_web);
  u16* whb   = (u16*)(w + o_whb);
  u16* fcwb  = (u16*)(w + o_fcwb);
  u16* encb  = (u16*)(w + o_encb);
  float* b01 = (float*)(w + o_b01);
  u16* x0b   = (u16*)(w + o_x0);
  float* encp= (float*)(w + o_encp);
  float* qb  = (float*)(w + o_q);
  u16* feat  = (u16*)(w + o_feat);
  u16* ring0 = (u16*)(w + o_ring);
  u16* ring1 = ring0 + 8 * 32768;
  int* done  = (int*)(w + o_done);
  float* sc  = (float*)(w + o_sc);
  float* part= (float*)(w + o_part);
  float* nllb= (float*)(w + o_nll);

  // zero rings + done counters (contiguous)
  hipMemsetAsync(w + o_ring, 0, (o_done - o_ring) + 512, stream);

  k_prep<<<4096, 256, 0, stream>>>(wih, whh, awe, awh, fcw, enc, bih, bhh,
                                   wihb, whhb, web, whb, fcwb, encb, b01);
  k_embed<<<4032, 256, 0, stream>>>(X, emb, ebf);

  // X0 = E @ Wih0^T + (bih0+bhh0): (4032,2048) K=512, bf16 output
  gemm_btb<<<dim3(63, 32), 256, 0, stream>>>(ebf, 512, wihb, 512, x0b, 2048, b01, 512);
  // enc_proj = enc @ We^T + attn_b: (4032,512) K=512 (rows b*63+e)
  gemm_bt<<<dim3(63, 8), 256, 0, stream>>>(encb, 512, web, 512, encp, 512, ab, 512);

  // pipelined LSTM: 64 WGs, layer-pipelined, aggregated tick counters
  lstm_pipe<<<64, 256, 0, stream>>>(whhb, wihb + 2048 * 512, whhb + 2048 * 512,
                                    x0b, b01 + 2048, ring0, ring1, feat, done);

  // q = top @ Wh^T: A = feat[:, :512] (lda=1024)
  gemm_bt<<<dim3(63, 8), 256, 0, stream>>>(feat, 1024, whb, 512, qb, 512, nullptr, 512);
  k_scores<<<4032, 256, 0, stream>>>(qb, encp, vw, sc);
  k_att<<<3969, 64, 0, stream>>>(sc, mask);
  k_weighted<<<4032, 256, 0, stream>>>(sc, enc, feat);

  gemm_fc<<<dim3(32, 250), 256, 0, stream>>>(feat, fcwb, fcb, part);
  k_rowstats<<<1008, 256, 0, stream>>>(part, feat, fcwb, fcb, X, nllb);
  k_final<<<1, 256, 0, stream>>>(nllb, X, out);
}

// Round 8
// 1270.494 us; speedup vs baseline: 1.4315x; 1.0461x over previous
//
#include <hip/hip_runtime.h>
#include <math.h>

// Problem constants: V=32000 D=512 H=512 L=2 B=64 S=64 -> T=Te=63
#define NEGV -1000000000.0f

typedef unsigned short u16;
typedef __attribute__((ext_vector_type(8))) short bf16x8;
typedef __attribute__((ext_vector_type(4))) float f32x4;

__device__ __forceinline__ u16 f2bf(float f){
  union { float f; unsigned u; } v; v.f = f;
  unsigned u = v.u;
  unsigned r = (u + 0x7fffu + ((u >> 16) & 1u)) >> 16;
  return (u16)r;
}
__device__ __forceinline__ float bf2f(u16 b){
  union { unsigned u; float f; } v; v.u = ((unsigned)b) << 16;
  return v.f;
}
__device__ __forceinline__ float sigmf(float x){ return 1.f / (1.f + __expf(-x)); }
__device__ __forceinline__ float tanhf_(float x){
  float e = __expf(-2.f * fabsf(x));
  float t = (1.f - e) / (1.f + e);
  return x >= 0.f ? t : -t;
}
__device__ __forceinline__ float wred64(float v){
  #pragma unroll
  for (int m = 32; m; m >>= 1) v += __shfl_xor(v, m, 64);
  return v;
}
__device__ __forceinline__ float wmax64(float v){
  #pragma unroll
  for (int m = 32; m; m >>= 1) v = fmaxf(v, __shfl_xor(v, m, 64));
  return v;
}

// ---- async global->LDS (16B/lane). LDS dest is wave-uniform base + lane*16. ----
typedef const __attribute__((address_space(1))) unsigned int* gas_ptr;
typedef __attribute__((address_space(3))) unsigned int* las_ptr;
__device__ __forceinline__ void gl_lds16(const u16* g, u16* l){
  __builtin_amdgcn_global_load_lds((gas_ptr)g, (las_ptr)l, 16, 0, 0);
}

// ---- agent-scope (sc1) write-through 2B store: h-ring data bypasses L1/L2 ----
__device__ __forceinline__ void st_sc1_u16(u16* p, unsigned v){
  asm volatile("global_store_short %0, %1, off sc1" :: "v"(p), "v"(v) : "memory");
}

// ---------------- prep: fp32 -> bf16 weight copies + bias sums (4-wide vectorized) ----------------
__device__ __forceinline__ void cvt4(u16* d, const float* s){
  float4 v = *(const float4*)s;
  union { u16 h[4]; uint2 u; } o;
  o.h[0] = f2bf(v.x); o.h[1] = f2bf(v.y); o.h[2] = f2bf(v.z); o.h[3] = f2bf(v.w);
  *(uint2*)d = o.u;
}
__global__ __launch_bounds__(256) void k_prep(
    const float* wih, const float* whh, const float* we, const float* wh,
    const float* fcw, const float* enc, const float* bih, const float* bhh,
    u16* wihb, u16* whhb, u16* web, u16* whb, u16* fcwb, u16* encb, float* b01)
{
  const long n0 = 2097152, n1 = 2097152, n2 = 262144, n3 = 262144;
  const long n4 = 32768000, n5 = 2064384, n6 = 4096;
  const long total4 = (n0 + n1 + n2 + n3 + n4 + n5 + n6) >> 2;
  long stride = (long)gridDim.x * 256;
  for (long i = (long)blockIdx.x * 256 + threadIdx.x; i < total4; i += stride){
    long j = i << 2;
    if (j < n0){ cvt4(wihb + j, wih + j); continue; } j -= n0;
    if (j < n1){ cvt4(whhb + j, whh + j); continue; } j -= n1;
    if (j < n2){ cvt4(web + j,  we + j);  continue; } j -= n2;
    if (j < n3){ cvt4(whb + j,  wh + j);  continue; } j -= n3;
    if (j < n4){ cvt4(fcwb + j, fcw + j); continue; } j -= n4;
    if (j < n5){ cvt4(encb + j, enc + j); continue; } j -= n5;
    float4 a = *(const float4*)(bih + j);
    float4 b = *(const float4*)(bhh + j);
    *(float4*)(b01 + j) = make_float4(a.x + b.x, a.y + b.y, a.z + b.z, a.w + b.w);
  }
}

// ---------------- embedding gather -> bf16 ----------------
__global__ __launch_bounds__(256) void k_embed(const int* X, const float* emb, u16* ebf){
  int row = blockIdx.x;            // t*64 + b
  int t = row >> 6, b = row & 63;
  int tok = X[b * 64 + t];         // X is (B=64, S=64)
  const float* src = emb + (long)tok * 512;
  u16* dst = ebf + (long)row * 512;
  for (int j = threadIdx.x; j < 512; j += 256) dst[j] = f2bf(src[j]);
}

// ---------------- generic bf16 GEMM: C(M,N) = A(M,K) @ B(N,K)^T + bias (fp32 out) ----------------
__global__ __launch_bounds__(256) void gemm_bt(
    const u16* Am, int lda, const u16* Bm, int ldb,
    float* C, int ldc, const float* bias, int K)
{
  __shared__ u16 sA[64 * 32], sB[64 * 32];
  int tm = blockIdx.x, tn = blockIdx.y;
  int tid = threadIdx.x;
  int wave = tid >> 6, lane = tid & 63;
  int wm = wave >> 1, wn = wave & 1;
  int q = lane >> 4, cl = lane & 15;
  f32x4 acc[2][2];
  #pragma unroll
  for (int i = 0; i < 2; i++)
    #pragma unroll
    for (int j = 0; j < 2; j++) acc[i][j] = (f32x4){0.f, 0.f, 0.f, 0.f};

  int r = tid >> 2, ck = tid & 3;
  const u16* Ags = Am + (long)(tm * 64 + r) * lda + ck * 8;
  const u16* Bgs = Bm + (long)(tn * 64 + r) * ldb + ck * 8;
  u16* sAw = &sA[wave * 512];
  u16* sBw = &sB[wave * 512];

  for (int kt = 0; kt < K; kt += 32){
    gl_lds16(Ags + kt, sAw);
    gl_lds16(Bgs + kt, sBw);
    __syncthreads();
    #pragma unroll
    for (int i = 0; i < 2; i++){
      bf16x8 af = *(const bf16x8*)&sA[(wm * 32 + i * 16 + cl) * 32 + q * 8];
      #pragma unroll
      for (int j = 0; j < 2; j++){
        bf16x8 bfv = *(const bf16x8*)&sB[(wn * 32 + j * 16 + cl) * 32 + q * 8];
        acc[i][j] = __builtin_amdgcn_mfma_f32_16x16x32_bf16(af, bfv, acc[i][j], 0, 0, 0);
      }
    }
    __syncthreads();
  }
  #pragma unroll
  for (int i = 0; i < 2; i++)
    #pragma unroll
    for (int j = 0; j < 2; j++){
      int colg = tn * 64 + wn * 32 + j * 16 + cl;
      float bv = bias ? bias[colg] : 0.f;
      #pragma unroll
      for (int rr = 0; rr < 4; rr++){
        int rowg = tm * 64 + wm * 32 + i * 16 + q * 4 + rr;
        C[(long)rowg * ldc + colg] = acc[i][j][rr] + bv;
      }
    }
}

// ---------------- same GEMM but bf16 output (for x0 gate pre-activations) ----------------
__global__ __launch_bounds__(256) void gemm_btb(
    const u16* Am, int lda, const u16* Bm, int ldb,
    u16* C, int ldc, const float* bias, int K)
{
  __shared__ u16 sA[64 * 32], sB[64 * 32];
  int tm = blockIdx.x, tn = blockIdx.y;
  int tid = threadIdx.x;
  int wave = tid >> 6, lane = tid & 63;
  int wm = wave >> 1, wn = wave & 1;
  int q = lane >> 4, cl = lane & 15;
  f32x4 acc[2][2];
  #pragma unroll
  for (int i = 0; i < 2; i++)
    #pragma unroll
    for (int j = 0; j < 2; j++) acc[i][j] = (f32x4){0.f, 0.f, 0.f, 0.f};

  int r = tid >> 2, ck = tid & 3;
  const u16* Ags = Am + (long)(tm * 64 + r) * lda + ck * 8;
  const u16* Bgs = Bm + (long)(tn * 64 + r) * ldb + ck * 8;
  u16* sAw = &sA[wave * 512];
  u16* sBw = &sB[wave * 512];

  for (int kt = 0; kt < K; kt += 32){
    gl_lds16(Ags + kt, sAw);
    gl_lds16(Bgs + kt, sBw);
    __syncthreads();
    #pragma unroll
    for (int i = 0; i < 2; i++){
      bf16x8 af = *(const bf16x8*)&sA[(wm * 32 + i * 16 + cl) * 32 + q * 8];
      #pragma unroll
      for (int j = 0; j < 2; j++){
        bf16x8 bfv = *(const bf16x8*)&sB[(wn * 32 + j * 16 + cl) * 32 + q * 8];
        acc[i][j] = __builtin_amdgcn_mfma_f32_16x16x32_bf16(af, bfv, acc[i][j], 0, 0, 0);
      }
    }
    __syncthreads();
  }
  #pragma unroll
  for (int i = 0; i < 2; i++)
    #pragma unroll
    for (int j = 0; j < 2; j++){
      int colg = tn * 64 + wn * 32 + j * 16 + cl;
      float bv = bias ? bias[colg] : 0.f;
      #pragma unroll
      for (int rr = 0; rr < 4; rr++){
        int rowg = tm * 64 + wm * 32 + i * 16 + q * 4 + rr;
        C[(long)rowg * ldc + colg] = f2bf(acc[i][j][rr] + bv);
      }
    }
}

// ---------------- pipelined LSTM: R3 form (measured best) — per-WG flags ----------------
__device__ __forceinline__ void wait_flags(int* flags, int tid, int need0, int need1){
  if (tid < 64){
    int need = (tid < 32) ? need0 : need1;
    for (;;){
      int v = __hip_atomic_load(flags + tid, __ATOMIC_RELAXED, __HIP_MEMORY_SCOPE_AGENT);
      if (__ballot(v >= need) == ~0ull) break;
    }
  }
  __syncthreads();
}

#define ISSUE_RING_FRAGS(afr, Ab)                                              \
  {                                                                            \
    _Pragma("unroll")                                                          \
    for (int kt = 0; kt < 16; kt++)                                            \
      asm volatile("global_load_dwordx4 %0, %1, off offset:%2 sc1"             \
                   : "=v"(afr[kt]) : "v"(Ab), "i"(kt * 64));                   \
  }
#define WAITCNT_VM(N)                                                          \
  { asm volatile("s_waitcnt vmcnt(" #N ")" ::: "memory");                      \
    __builtin_amdgcn_sched_barrier(0); }

__global__ __launch_bounds__(256, 1) void lstm_pipe(
    const u16* whh0, const u16* wih1, const u16* whh1,
    const u16* x0b, const float* b1s,
    u16* ring0, u16* ring1, u16* feat, int* flags)
{
  __shared__ u16 sW[32768];    // layer0: Whh0 slice; layer1: Whh1 slice (recurrent B)
  __shared__ u16 sW2[32768];   // layer1 only: Wih1 slice (input-term B)
  int wg = blockIdx.x;
  int layer = wg >> 5;
  int cc = (wg & 31) * 16;
  int tid = threadIdx.x;
  int wave = tid >> 6, lane = tid & 63;
  int q = lane >> 4, cl = lane & 15;
  int j = cc + cl;

  {
    const u16* src = layer ? whh1 : whh0;
    for (int ch = tid; ch < 4096; ch += 256){
      int row = ch >> 6, c = ch & 63;
      int g = row >> 4, r = row & 15;
      *(uint4*)&sW[((c * 4 + g) * 16 + r) * 8] =
          *(const uint4*)&src[(long)(g * 512 + cc + r) * 512 + c * 8];
      if (layer)
        *(uint4*)&sW2[((c * 4 + g) * 16 + r) * 8] =
            *(const uint4*)&wih1[(long)(g * 512 + cc + r) * 512 + c * 8];
    }
  }
  __syncthreads();

  float cst[4] = {0.f, 0.f, 0.f, 0.f};
  float bg[4];
  if (layer){
    #pragma unroll
    for (int g = 0; g < 4; g++) bg[g] = b1s[g * 512 + j];
  }

  int foff = (wave * 16 + cl) * 512 + q * 8;

  for (int t = 0; t < 63; t++){
    f32x4 acc[4];
    #pragma unroll
    for (int g = 0; g < 4; g++) acc[g] = (f32x4){0.f, 0.f, 0.f, 0.f};

    if (layer == 0){
      float xg[4][4];
      #pragma unroll
      for (int rr = 0; rr < 4; rr++){
        int s = wave * 16 + q * 4 + rr;
        const u16* xr = x0b + (long)(t * 64 + s) * 2048 + j;
        #pragma unroll
        for (int g = 0; g < 4; g++) xg[g][rr] = bf2f(xr[g * 512]);
      }
      wait_flags(flags, tid, t, t - 7);
      {
        const u16* Ab = ring0 + ((t + 7) & 7) * 32768 + foff;
        bf16x8 afr[16];
        ISSUE_RING_FRAGS(afr, Ab);
        WAITCNT_VM(0);
        #pragma unroll
        for (int kt = 0; kt < 16; kt++)
          #pragma unroll
          for (int g = 0; g < 4; g++){
            bf16x8 bfv = *(const bf16x8*)&sW[(((kt * 4 + q) * 4 + g) * 16 + cl) * 8];
            acc[g] = __builtin_amdgcn_mfma_f32_16x16x32_bf16(afr[kt], bfv, acc[g], 0, 0, 0);
          }
      }
      u16* hn = ring0 + (t & 7) * 32768;
      #pragma unroll
      for (int rr = 0; rr < 4; rr++){
        int s = wave * 16 + q * 4 + rr;
        float gi = acc[0][rr] + xg[0][rr];
        float gf = acc[1][rr] + xg[1][rr];
        float gg = acc[2][rr] + xg[2][rr];
        float go = acc[3][rr] + xg[3][rr];
        float cn = sigmf(gf) * cst[rr] + sigmf(gi) * tanhf_(gg);
        cst[rr] = cn;
        st_sc1_u16(hn + s * 512 + j, (unsigned)f2bf(sigmf(go) * tanhf_(cn)));
      }
    } else {
      wait_flags(flags, tid, t + 1, t);
      const u16* Ab1 = ring1 + ((t + 7) & 7) * 32768 + foff;   // h1(t-1)
      const u16* Ab0 = ring0 + (t & 7) * 32768 + foff;         // h0(t)
      bf16x8 a1[16], a0[16];
      ISSUE_RING_FRAGS(a1, Ab1);
      ISSUE_RING_FRAGS(a0, Ab0);
      WAITCNT_VM(16);
      #pragma unroll
      for (int kt = 0; kt < 16; kt++)
        #pragma unroll
        for (int g = 0; g < 4; g++){
          bf16x8 bfv = *(const bf16x8*)&sW[(((kt * 4 + q) * 4 + g) * 16 + cl) * 8];
          acc[g] = __builtin_amdgcn_mfma_f32_16x16x32_bf16(a1[kt], bfv, acc[g], 0, 0, 0);
        }
      WAITCNT_VM(0);
      #pragma unroll
      for (int kt = 0; kt < 16; kt++)
        #pragma unroll
        for (int g = 0; g < 4; g++){
          bf16x8 bfv = *(const bf16x8*)&sW2[(((kt * 4 + q) * 4 + g) * 16 + cl) * 8];
          acc[g] = __builtin_amdgcn_mfma_f32_16x16x32_bf16(a0[kt], bfv, acc[g], 0, 0, 0);
        }
      u16* hn = ring1 + (t & 7) * 32768;
      #pragma unroll
      for (int rr = 0; rr < 4; rr++){
        int s = wave * 16 + q * 4 + rr;
        float gi = acc[0][rr] + bg[0];
        float gf = acc[1][rr] + bg[1];
        float gg = acc[2][rr] + bg[2];
        float go = acc[3][rr] + bg[3];
        float cn = sigmf(gf) * cst[rr] + sigmf(gi) * tanhf_(gg);
        cst[rr] = cn;
        u16 hb = f2bf(sigmf(go) * tanhf_(cn));
        st_sc1_u16(hn + s * 512 + j, (unsigned)hb);
        feat[(long)(t * 64 + s) * 1024 + j] = hb;
      }
    }
    asm volatile("s_waitcnt vmcnt(0)" ::: "memory");
    __syncthreads();
    if (tid == 0)
      __hip_atomic_store(flags + wg, t + 1, __ATOMIC_RELAXED, __HIP_MEMORY_SCOPE_AGENT);
  }
}

// ---------------- attention scores ----------------
__global__ __launch_bounds__(256) void k_scores(
    const float* qb, const float* encp, const float* vw, float* scores)
{
  int row = blockIdx.x;       // t*64 + b
  int b = row & 63;
  int wave = threadIdx.x >> 6, lane = threadIdx.x & 63;
  float qv[8], vwv[8];
  const float* qr = qb + (long)row * 512 + lane * 8;
  #pragma unroll
  for (int i = 0; i < 8; i++){ qv[i] = qr[i]; vwv[i] = vw[lane * 8 + i]; }
  for (int e = wave; e < 63; e += 4){
    const float* er = encp + (long)(b * 63 + e) * 512 + lane * 8;
    float s = 0.f;
    #pragma unroll
    for (int i = 0; i < 8; i++) s += vwv[i] * tanhf_(qv[i] + er[i]);
    s = wred64(s);
    if (lane == 0) scores[(long)row * 63 + e] = s;
  }
}

// ---------------- softmax over BATCH axis (reference quirk), in-place ----------------
__global__ __launch_bounds__(64) void k_att(float* scores, const unsigned char* mask){
  int idx = blockIdx.x;            // t*63 + e
  int t = idx / 63, e = idx - t * 63;
  int lane = threadIdx.x;          // = b
  long off = (long)(t * 64 + lane) * 63 + e;
  float s = scores[off];
  if (mask[((t + 62) % 63) * 63 + e]) s = NEGV;   // (t-1) mod 63
  float M = wmax64(s);
  float p = __expf(s - M);
  float S = wred64(p);
  scores[off] = p / S;
}

// ---------------- weighted[t,b,h] = sum_e att[t,b,e]*enc[b,e,h] -> feat[:,512:1024] ----------------
__global__ __launch_bounds__(256) void k_weighted(
    const float* att, const float* enc, u16* feat)
{
  int row = blockIdx.x;   // t*64 + b
  int b = row & 63;
  int j = threadIdx.x;
  float a0 = 0.f, a1 = 0.f;
  const float* ar = att + (long)row * 63;
  const float* er = enc + (long)b * 63 * 512;
  for (int e = 0; e < 63; e++){
    float a = ar[e];
    a0 += a * er[(long)e * 512 + j];
    a1 += a * er[(long)e * 512 + j + 256];
  }
  feat[(long)row * 1024 + 512 + j] = f2bf(a0);
  feat[(long)row * 1024 + 768 + j] = f2bf(a1);
}

// ---------------- fc GEMM: 256x256 tile, BK=64, 512 threads, dbuf, swizzled LDS ----------------
// A = feat (4096,1024) bf16, B = fc_W (32000,1024) bf16. grid (16, 125). K-tiles: 16.
// LDS: logical row-major [256 rows][64 K] per operand; chunk-level XOR swizzle:
// 16B chunk (row, kc) lives at physical chunk row*8 + (kc ^ (row&7)) — bijective
// involution applied on BOTH staging source and ds_read address (rule #21).
// Fragment reads (64 lanes, same col-range, different rows) hit distinct bank
// groups -> 2-way aliasing only (free, m136). Staging stays 128B-coalesced.
// Schedule per K-tile: issue 8 gl_lds for next tile -> 2x(12 ds_read + 32 MFMA
// w/ setprio) -> vmcnt(0) -> ONE barrier. 16 barriers total (vs 64 in R6 form).
// __launch_bounds__(512, 1): occupancy is LDS-bound (136KB -> 1 WG/CU) anyway;
// the ,1 keeps the VGPR budget at 512 so register allocation cannot fail.
__global__ __launch_bounds__(512, 1) void gemm_fc(
    const u16* Am, const u16* Bm, const float* fcb, float* partials)
{
  __shared__ u16 sA[2][16384], sB[2][16384];   // 128 KB
  __shared__ float sm[256][4], ss[256][4];     // 8 KB
  int tm = blockIdx.x, tn = blockIdx.y;
  int tid = threadIdx.x;
  int wave = tid >> 6, lane = tid & 63;
  int wm = wave >> 2, wn = wave & 3;           // 2 x 4 wave grid
  int q = lane >> 4, cl = lane & 15;

  f32x4 acc[8][4];
  #pragma unroll
  for (int i = 0; i < 8; i++)
    #pragma unroll
    for (int j = 0; j < 4; j++) acc[i][j] = (f32x4){0.f, 0.f, 0.f, 0.f};

  // staging pointers (4 chunks each for A and B) + wave-uniform LDS dest bases
  const u16 *pA[4], *pB[4];
  int sdst[4];
  #pragma unroll
  for (int h = 0; h < 4; h++){
    int c = tid + h * 512;
    int row = c >> 3;
    int kc = (c & 7) ^ (row & 7);
    pA[h] = Am + (long)(tm * 256 + row) * 1024 + kc * 8;
    pB[h] = Bm + (long)(tn * 256 + row) * 1024 + kc * 8;
    sdst[h] = (h * 512 + wave * 64) * 8;   // u16 index of wave-uniform base
  }
  // per-lane fragment read offsets (u16 units); row&7 == cl&7 for all fragment rows
  int r0 = cl * 64;
  int ex = (cl & 7) * 16;
  int e0 = ((q * 16) ^ ex) >> 1;
  int e1 = ((64 + q * 16) ^ ex) >> 1;

  // prologue: stage K-tile 0
  #pragma unroll
  for (int h = 0; h < 4; h++){
    gl_lds16(pA[h], &sA[0][sdst[h]]);
    gl_lds16(pB[h], &sB[0][sdst[h]]);
  }
  asm volatile("s_waitcnt vmcnt(0)" ::: "memory");
  __syncthreads();

  for (int k = 0; k < 16; k++){
    int cur = k & 1;
    if (k < 15){
      int adv = (k + 1) * 64;
      #pragma unroll
      for (int h = 0; h < 4; h++){
        gl_lds16(pA[h] + adv, &sA[cur ^ 1][sdst[h]]);
        gl_lds16(pB[h] + adv, &sB[cur ^ 1][sdst[h]]);
      }
    }
    #pragma unroll
    for (int ks = 0; ks < 2; ks++){
      int eo = ks ? e1 : e0;
      bf16x8 af[8], bf[4];
      #pragma unroll
      for (int mt = 0; mt < 8; mt++)
        af[mt] = *(const bf16x8*)&sA[cur][(wm * 8 + mt) * 1024 + r0 + eo];
      #pragma unroll
      for (int nt = 0; nt < 4; nt++)
        bf[nt] = *(const bf16x8*)&sB[cur][(wn * 4 + nt) * 1024 + r0 + eo];
      __builtin_amdgcn_s_setprio(1);
      #pragma unroll
      for (int nt = 0; nt < 4; nt++)
        #pragma unroll
        for (int mt = 0; mt < 8; mt++)
          acc[mt][nt] = __builtin_amdgcn_mfma_f32_16x16x32_bf16(af[mt], bf[nt], acc[mt][nt], 0, 0, 0);
      __builtin_amdgcn_s_setprio(0);
    }
    asm volatile("s_waitcnt vmcnt(0)" ::: "memory");
    __syncthreads();
  }

  // fused rowwise logsumexp over this 256-col tile
  float fb[4];
  #pragma unroll
  for (int nt = 0; nt < 4; nt++) fb[nt] = fcb[tn * 256 + wn * 64 + nt * 16 + cl];
  #pragma unroll
  for (int mt = 0; mt < 8; mt++){
    #pragma unroll
    for (int rr = 0; rr < 4; rr++){
      float vals[4];
      float vm = -3.0e38f, vs = 0.f;
      #pragma unroll
      for (int nt = 0; nt < 4; nt++){ float v = acc[mt][nt][rr] + fb[nt]; vals[nt] = v; vm = fmaxf(vm, v); }
      #pragma unroll
      for (int nt = 0; nt < 4; nt++) vs += __expf(vals[nt] - vm);
      #pragma unroll
      for (int m = 1; m < 16; m <<= 1){
        float om = __shfl_xor(vm, m, 16);
        float os = __shfl_xor(vs, m, 16);
        float nm = fmaxf(vm, om);
        vs = vs * __expf(vm - nm) + os * __expf(om - nm);
        vm = nm;
      }
      if (cl == 0){
        int rl = wm * 128 + mt * 16 + q * 4 + rr;
        sm[rl][wn] = vm; ss[rl][wn] = vs;
      }
    }
  }
  __syncthreads();
  if (tid < 256){
    float M = -3.0e38f;
    #pragma unroll
    for (int w = 0; w < 4; w++) M = fmaxf(M, sm[tid][w]);
    float S = 0.f;
    #pragma unroll
    for (int w = 0; w < 4; w++) S += ss[tid][w] * __expf(sm[tid][w] - M);
    long row = tm * 256 + tid;
    partials[(row * 125 + tn) * 2]     = M;
    partials[(row * 125 + tn) * 2 + 1] = S;
  }
}

// ---------------- per-row logsumexp combine + target logit -> nll ----------------
__global__ __launch_bounds__(256) void k_rowstats(
    const float* partials, const u16* feat, const u16* fcwb,
    const float* fcb, const int* X, float* nll)
{
  int row = blockIdx.x * 4 + (threadIdx.x >> 6);
  int lane = threadIdx.x & 63;
  if (row >= 4032) return;
  float vm = -3.0e38f, vs = 0.f;
  const float* pr = partials + (long)row * 250;
  for (int i = lane; i < 125; i += 64){
    float m = pr[i * 2], s2 = pr[i * 2 + 1];
    float nm = fmaxf(vm, m);
    vs = vs * __expf(vm - nm) + s2 * __expf(m - nm);
    vm = nm;
  }
  #pragma unroll
  for (int m = 32; m; m >>= 1){
    float om = __shfl_xor(vm, m, 64);
    float os = __shfl_xor(vs, m, 64);
    float nm = fmaxf(vm, om);
    vs = vs * __expf(vm - nm) + os * __expf(om - nm);
    vm = nm;
  }
  float logZ = vm + __logf(vs);
  int t = row >> 6, b = row & 63;
  int tgt = X[b * 64 + t + 1];
  const u16* fr = feat + (long)row * 1024 + lane * 16;
  const u16* wr = fcwb + (long)tgt * 1024 + lane * 16;
  float d = 0.f;
  #pragma unroll
  for (int i = 0; i < 16; i++) d += bf2f(fr[i]) * bf2f(wr[i]);
  d = wred64(d);
  if (lane == 0) nll[row] = logZ - (d + fcb[tgt]);
}

// ---------------- final masked mean ----------------
__global__ __launch_bounds__(256) void k_final(const float* nll, const int* X, float* out){
  __shared__ float lt[64];
  int wave = threadIdx.x >> 6, lane = threadIdx.x & 63;
  for (int t = wave; t < 63; t += 4){
    int tgt = X[lane * 64 + t + 1];
    float v = (tgt != 0) ? nll[t * 64 + lane] : 0.f;
    float c = (tgt != 0) ? 1.f : 0.f;
    v = wred64(v); c = wred64(c);
    if (lane == 0) lt[t] = v / c;
  }
  __syncthreads();
  if (threadIdx.x == 0){
    float s = 0.f;
    for (int t = 0; t < 63; t++) s += lt[t];
    out[0] = s / 63.f;
  }
}

extern "C" void kernel_launch(void* const* d_in, const int* in_sizes, int n_in,
                              void* d_out, int out_size, void* d_ws, size_t ws_size,
                              hipStream_t stream)
{
  (void)in_sizes; (void)n_in; (void)out_size; (void)ws_size;
  const int*   X    = (const int*)d_in[0];
  const float* enc  = (const float*)d_in[1];
  const unsigned char* mask = (const unsigned char*)d_in[2];
  const float* emb  = (const float*)d_in[3];
  const float* wih  = (const float*)d_in[4];
  const float* whh  = (const float*)d_in[5];
  const float* bih  = (const float*)d_in[6];
  const float* bhh  = (const float*)d_in[7];
  const float* awh  = (const float*)d_in[8];
  const float* awe  = (const float*)d_in[9];
  const float* ab   = (const float*)d_in[10];
  const float* vw   = (const float*)d_in[11];
  const float* fcw  = (const float*)d_in[12];
  const float* fcb  = (const float*)d_in[13];
  float* out = (float*)d_out;

  char* w = (char*)d_ws;
  size_t o = 0;
  auto alloc = [&](size_t bytes){ size_t r = o; o = (o + bytes + 255) & ~(size_t)255; return r; };
  size_t o_ebf  = alloc((size_t)4032 * 512 * 2);
  size_t o_wihb = alloc((size_t)2 * 2048 * 512 * 2);
  size_t o_whhb = alloc((size_t)2 * 2048 * 512 * 2);
  size_t o_web  = alloc((size_t)512 * 512 * 2);
  size_t o_whb  = alloc((size_t)512 * 512 * 2);
  size_t o_fcwb = alloc((size_t)32000 * 1024 * 2);
  size_t o_encb = alloc((size_t)4032 * 512 * 2);
  size_t o_b01  = alloc((size_t)4096 * 4);
  size_t o_x0   = alloc((size_t)4032 * 2048 * 2);        // bf16
  size_t o_encp = alloc((size_t)4032 * 512 * 4);
  size_t o_q    = alloc((size_t)4032 * 512 * 4);
  size_t o_feat = alloc((size_t)4096 * 1024 * 2);
  size_t o_ring = alloc((size_t)2 * 8 * 32768 * 2);      // ring0 + ring1 (depth 8)
  size_t o_flags= alloc((size_t)512);
  size_t o_sc   = alloc((size_t)63 * 64 * 63 * 4);
  size_t o_part = alloc((size_t)4096 * 250 * 2 * 4);
  size_t o_nll  = alloc((size_t)4032 * 4);

  u16* ebf   = (u16*)(w + o_ebf);
  u16* wihb  = (u16*)(w + o_wihb);
  u16* whhb  = (u16*)(w + o_whhb);
  u16* web   = (u16*)(w + o_web);
  u16* whb   = (u16*)(w + o_whb);
  u16* fcwb  = (u16*)(w + o_fcwb);
  u16* encb  = (u16*)(w + o_encb);
  float* b01 = (float*)(w + o_b01);
  u16* x0b   = (u16*)(w + o_x0);
  float* encp= (float*)(w + o_encp);
  float* qb  = (float*)(w + o_q);
  u16* feat  = (u16*)(w + o_feat);
  u16* ring0 = (u16*)(w + o_ring);
  u16* ring1 = ring0 + 8 * 32768;
  int* flags = (int*)(w + o_flags);
  float* sc  = (float*)(w + o_sc);
  float* part= (float*)(w + o_part);
  float* nllb= (float*)(w + o_nll);

  // zero rings + flags (contiguous)
  hipMemsetAsync(w + o_ring, 0, (o_flags - o_ring) + 512, stream);

  k_prep<<<4096, 256, 0, stream>>>(wih, whh, awe, awh, fcw, enc, bih, bhh,
                                   wihb, whhb, web, whb, fcwb, encb, b01);
  k_embed<<<4032, 256, 0, stream>>>(X, emb, ebf);

  // X0 = E @ Wih0^T + (bih0+bhh0): (4032,2048) K=512, bf16 output
  gemm_btb<<<dim3(63, 32), 256, 0, stream>>>(ebf, 512, wihb, 512, x0b, 2048, b01, 512);
  // enc_proj = enc @ We^T + attn_b: (4032,512) K=512 (rows b*63+e)
  gemm_bt<<<dim3(63, 8), 256, 0, stream>>>(encb, 512, web, 512, encp, 512, ab, 512);

  // pipelined LSTM: R3 form, 64 WGs, per-WG flags
  lstm_pipe<<<64, 256, 0, stream>>>(whhb, wihb + 2048 * 512, whhb + 2048 * 512,
                                    x0b, b01 + 2048, ring0, ring1, feat, flags);

  // q = top @ Wh^T: A = feat[:, :512] (lda=1024)
  gemm_bt<<<dim3(63, 8), 256, 0, stream>>>(feat, 1024, whb, 512, qb, 512, nullptr, 512);
  k_scores<<<4032, 256, 0, stream>>>(qb, encp, vw, sc);
  k_att<<<3969, 64, 0, stream>>>(sc, mask);
  k_weighted<<<4032, 256, 0, stream>>>(sc, enc, feat);

  gemm_fc<<<dim3(16, 125), 512, 0, stream>>>(feat, fcwb, fcb, part);
  k_rowstats<<<1008, 256, 0, stream>>>(part, feat, fcwb, fcb, X, nllb);
  k_final<<<1, 256, 0, stream>>>(nllb, X, out);
}